// Round 1
// baseline (253.740 us; speedup 1.0000x reference)
//
#include <hip/hip_runtime.h>

#define W_   160
#define H_   96
#define C_   128
#define B_   16
#define NBX  5
#define NBY  6
#define TX   32
#define TY   16
#define PXN  8
#define ROWS 24                 // TY + 8 halo rows
#define RSTR 44                 // padded row stride (floats): bank-conflict-free b128 windows
#define CSIZE (ROWS * RSTR)     // 1056 floats per channel slice
#define CCH  4                  // channels per LDS chunk
#define CHUNKF (CCH * CSIZE)    // 4224 floats
#define NCHUNK (C_ / CCH)       // 32
#define NTHR 576                // 9 waves, wave w -> dy = w-4
#define NSLOT (CHUNKF / 4)      // 1056 16B staging slots

__global__ __launch_bounds__(NTHR) void corr_kernel(
    const float* __restrict__ in1,
    const float* __restrict__ in2,
    float* __restrict__ out)
{
    __shared__ float lds[2 * CHUNKF];   // 33792 B, double-buffered in2 chunk

    // XCD-chunked bijective swizzle: 480 blocks = 8 XCDs * 60
    const int sb  = (blockIdx.x & 7) * 60 + (blockIdx.x >> 3);
    const int b   = sb / 30;
    const int rem = sb % 30;
    const int by  = rem / NBX;
    const int bx  = rem % NBX;
    const int x0 = bx * TX, y0 = by * TY;

    const size_t HW = (size_t)H_ * W_;
    const float* i1b = in1 + (size_t)b * C_ * HW;
    const float* i2b = in2 + (size_t)b * C_ * HW;

    const int tid  = threadIdx.x;
    const int wv   = tid >> 6;      // 0..8 ; dy = wv - 4
    const int lane = tid & 63;
    const int q    = lane & 3;      // x-quad (8 px each)
    const int r    = lane >> 2;     // row 0..15

    // ---- staging slot decode (constant per thread) ----
    // slot s covers floats [4s, 4s+4) of layout [CCH][ROWS][RSTR]
    const int s0 = tid;
    const int s1 = tid + NTHR;
    const bool live1 = (s1 < NSLOT);

    const int e0   = s0 * 4;
    const int cl0  = e0 / CSIZE;
    const int rr0  = e0 % CSIZE;
    const int row0 = rr0 / RSTR;
    const int col0 = rr0 % RSTR;          // multiple of 4
    const int gy0  = y0 - 4 + row0;
    const int gx0  = x0 - 4 + col0;
    const bool v0  = ((unsigned)gy0 < (unsigned)H_) && ((unsigned)gx0 <= (unsigned)(W_ - 4));
    const long src0 = (long)cl0 * (long)HW + (long)gy0 * W_ + gx0;   // only deref'd when v0

    const int e1   = (live1 ? s1 : 0) * 4;
    const int cl1  = e1 / CSIZE;
    const int rr1  = e1 % CSIZE;
    const int row1 = rr1 / RSTR;
    const int col1 = rr1 % RSTR;
    const int gy1  = y0 - 4 + row1;
    const int gx1  = x0 - 4 + col1;
    const bool v1  = ((unsigned)gy1 < (unsigned)H_) && ((unsigned)gx1 <= (unsigned)(W_ - 4));
    const long src1 = (long)cl1 * (long)HW + (long)gy1 * W_ + gx1;

    const float4 z4 = {0.f, 0.f, 0.f, 0.f};
    float4 n0, n1;

    // ---- prologue: stage chunk 0 into buffer 0 ----
    n0 = v0 ? *(const float4*)(i2b + src0) : z4;
    n1 = (live1 && v1) ? *(const float4*)(i2b + src1) : z4;
    *(float4*)(lds + 4 * s0) = n0;
    if (live1) *(float4*)(lds + 4 * s1) = n1;
    __syncthreads();

    float acc[PXN][9];
#pragma unroll
    for (int p = 0; p < PXN; ++p)
#pragma unroll
        for (int d = 0; d < 9; ++d) acc[p][d] = 0.f;

    const float* a0p = i1b + (size_t)(y0 + r) * W_ + (x0 + q * PXN);
    const int woff = (r + wv) * RSTR + q * PXN;   // window start: local col 8q (= global x0+8q-4)

    for (int ch = 0; ch < NCHUNK; ++ch) {
        const float* cbuf = lds + (ch & 1) * CHUNKF;
        const bool more = (ch + 1) < NCHUNK;
        if (more) {
            const long cadd = (long)(ch + 1) * CCH * (long)HW;
            n0 = v0 ? *(const float4*)(i2b + cadd + src0) : z4;
            n1 = (live1 && v1) ? *(const float4*)(i2b + cadd + src1) : z4;
        }
#pragma unroll
        for (int cc = 0; cc < CCH; ++cc) {
            const float* ap = a0p + (size_t)(ch * CCH + cc) * HW;
            const float4 a0 = *(const float4*)(ap);
            const float4 a1 = *(const float4*)(ap + 4);
            const float* wp = cbuf + cc * CSIZE + woff;
            const float4 w0 = *(const float4*)(wp);
            const float4 w1 = *(const float4*)(wp + 4);
            const float4 w2 = *(const float4*)(wp + 8);
            const float4 w3 = *(const float4*)(wp + 12);
            const float av[8] = {a0.x, a0.y, a0.z, a0.w, a1.x, a1.y, a1.z, a1.w};
            const float wf[16] = {w0.x, w0.y, w0.z, w0.w,  w1.x, w1.y, w1.z, w1.w,
                                  w2.x, w2.y, w2.z, w2.w,  w3.x, w3.y, w3.z, w3.w};
#pragma unroll
            for (int p = 0; p < PXN; ++p)
#pragma unroll
                for (int d = 0; d < 9; ++d)
                    acc[p][d] = fmaf(av[p], wf[p + d], acc[p][d]);
        }
        if (more) {
            float* obuf = lds + ((ch + 1) & 1) * CHUNKF;
            *(float4*)(obuf + 4 * s0) = n0;
            if (live1) *(float4*)(obuf + 4 * s1) = n1;
        }
        __syncthreads();
    }

    // ---- epilogue: out[b][wv*9+d][y][x] = acc/128 ----
    const float sc = 1.0f / 128.0f;
    const size_t obase = (((size_t)b * 81 + (size_t)wv * 9) * H_ + (y0 + r)) * W_ + (x0 + q * PXN);
#pragma unroll
    for (int d = 0; d < 9; ++d) {
        float4 o0, o1;
        o0.x = acc[0][d] * sc; o0.y = acc[1][d] * sc; o0.z = acc[2][d] * sc; o0.w = acc[3][d] * sc;
        o1.x = acc[4][d] * sc; o1.y = acc[5][d] * sc; o1.z = acc[6][d] * sc; o1.w = acc[7][d] * sc;
        float* op = out + obase + (size_t)d * HW;
        *(float4*)(op)     = o0;
        *(float4*)(op + 4) = o1;
    }
}

extern "C" void kernel_launch(void* const* d_in, const int* in_sizes, int n_in,
                              void* d_out, int out_size, void* d_ws, size_t ws_size,
                              hipStream_t stream) {
    const float* in1 = (const float*)d_in[0];
    const float* in2 = (const float*)d_in[1];
    float* out = (float*)d_out;
    (void)in_sizes; (void)n_in; (void)out_size; (void)d_ws; (void)ws_size;
    hipLaunchKernelGGL(corr_kernel, dim3(B_ * NBX * NBY), dim3(NTHR), 0, stream,
                       in1, in2, out);
}